// Round 10
// baseline (247.614 us; speedup 1.0000x reference)
//
#include <hip/hip_runtime.h>
#include <hip/hip_bf16.h>
#include <stdint.h>

#define NROWS   65536
#define RPB     32
#define NBLK    (NROWS/RPB)       // 2048
#define H2N     100
#define KPAD    128
#define N3      1224
#define OUTW    2193
#define TAILN   969
#define T1OFF   77
#define NTILE   138               // 77 main + 61 pair logical slots
#define NTOT    199               // frag tiles in w3f
#define NPANEL  18                // 18 panels x 8 slots
#define PSTR    132               // f32 row stride of LDS panel

typedef __attribute__((ext_vector_type(8))) short bf16x8;
typedef __attribute__((ext_vector_type(4))) float f32x4;
typedef f32x4 f32x4_a4 __attribute__((aligned(4)));   // 4-byte-aligned view for nt stores

__device__ __forceinline__ float fast_sigmoid(float z){
    return __builtin_amdgcn_rcpf(1.0f + __expf(-z));
}
__device__ __forceinline__ unsigned short f2bf(float v){
    __hip_bfloat16 h = __float2bfloat16(v);
    return *reinterpret_cast<unsigned short*>(&h);
}
__device__ __forceinline__ void store16_nt(float* p, f32x4 v){
    __builtin_nontemporal_store(v, (f32x4_a4*)p);     // L2-bypass streaming store
}

// w3f[((t*4+ks)*64+lane)*8+e] = bf16(W3[k=ks*32+(lane>>4)*8+e][srccol(t,lane&15)])
// frag tiles: 0..76 main; 77..137 gathered c1; 138..198 gathered c2.
__global__ void prep_kernel(const float* __restrict__ W3,
                            const float* __restrict__ b3,
                            const float* __restrict__ wgt,
                            const int* __restrict__ idx1,
                            const int* __restrict__ idx2,
                            unsigned short* __restrict__ w3f,
                            float* __restrict__ b3f,
                            float* __restrict__ pwf){
    const int t    = blockIdx.x;
    const int ks   = threadIdx.x >> 6;
    const int lane = threadIdx.x & 63;
    const int lm   = lane & 15, lgf = lane >> 4;

    int col = -1;
    if (t < T1OFF){
        int c = t * 16 + lm;
        if (c < N3) col = c;
    } else if (t < NTILE){
        int p = (t - T1OFF) * 16 + lm;
        if (p < TAILN){ int j = p / 17; col = idx1[j] * 17 + (p - j * 17); }
    } else {
        int p = (t - NTILE) * 16 + lm;
        if (p < TAILN){ int j = p / 17; col = idx2[j] * 17 + (p - j * 17); }
    }

    unsigned short vals[8];
    #pragma unroll
    for (int e = 0; e < 8; ++e){
        int k = ks * 32 + lgf * 8 + e;
        float v = (col >= 0 && k < H2N) ? W3[k * N3 + col] : 0.0f;
        vals[e] = f2bf(v);
    }
    *reinterpret_cast<bf16x8*>(w3f + ((size_t)(t * 4 + ks) * 64 + lane) * 8)
        = *reinterpret_cast<bf16x8*>(vals);

    if (ks == 0 && lgf == 0)
        b3f[t * 16 + lm] = (col >= 0) ? b3[col] : 0.0f;
    if (ks == 0 && lgf == 1 && t >= T1OFF && t < NTILE){
        int p = (t - T1OFF) * 16 + lm;
        pwf[(t - T1OFF) * 16 + lm] = (p < TAILN) ? wgt[p / 17] : 0.0f;
    }
}

__global__ __launch_bounds__(256, 3)
void snn_kernel(const float* __restrict__ x,
                const float* __restrict__ W1, const float* __restrict__ b1,
                const float* __restrict__ W2, const float* __restrict__ b2,
                const unsigned short* __restrict__ w3f,
                const float* __restrict__ b3f,
                const float* __restrict__ pwf,
                float* __restrict__ out)
{
    __shared__ __align__(16) unsigned short lds_h2[RPB][KPAD];   // 8 KB
    __shared__ float lds_h1[RPB][10];                            // 1.25 KB
    __shared__ __align__(16) float lds_p[2][RPB][PSTR];          // 33.8 KB (double-buffered)

    const int t    = threadIdx.x;
    const int row0 = blockIdx.x * RPB;

    // ---- layer 1
    for (int i = t; i < RPB * 10; i += 256){
        int r = i / 10, j = i - r * 10;
        lds_h1[r][j] = fast_sigmoid(x[row0 + r] * W1[j] + b1[j]);
    }
    __syncthreads();

    // ---- layer 2 -> bf16 LDS (k 100..127 zero-padded)
    for (int i = t; i < RPB * KPAD; i += 256){
        int r = i >> 7, c = i & 127;
        float v = 0.0f;
        if (c < H2N){
            float z = b2[c];
            #pragma unroll
            for (int j = 0; j < 10; ++j) z += lds_h1[r][j] * W2[j * H2N + c];
            v = fast_sigmoid(z);
        }
        lds_h2[r][c] = f2bf(v);
    }
    __syncthreads();

    const int lane = t & 63, wid = t >> 6;
    const int lm = lane & 15, lg = lane >> 4;
    const int l5 = lane & 31, lh = lane >> 5;

    bf16x8 hfr[2][4];
    #pragma unroll
    for (int rt = 0; rt < 2; ++rt)
        #pragma unroll
        for (int ks = 0; ks < 4; ++ks)
            hfr[rt][ks] = *reinterpret_cast<const bf16x8*>(&lds_h2[rt * 16 + lm][ks * 32 + lg * 8]);

    #define LOADFRAG(dst, tile) do {                                              \
        const unsigned short* bp_ = w3f + ((size_t)((tile) * 4) * 64 + lane) * 8; \
        _Pragma("unroll")                                                         \
        for (int ks_ = 0; ks_ < 4; ++ks_)                                         \
            dst[ks_] = *reinterpret_cast<const bf16x8*>(bp_ + (size_t)ks_ * 512); \
    } while(0)

    auto MFMA8 = [&](bf16x8 (&cf)[4], f32x4 (&acc)[2]){
        acc[0] = f32x4{0,0,0,0}; acc[1] = f32x4{0,0,0,0};
        #pragma unroll
        for (int ks = 0; ks < 4; ++ks)
            #pragma unroll
            for (int rt = 0; rt < 2; ++rt)
                acc[rt] = __builtin_amdgcn_mfma_f32_16x16x32_bf16(cf[ks], hfr[rt][ks], acc[rt], 0, 0, 0);
    };

    auto PREFETCH = [&](int p, bf16x8 (&f1)[4], bf16x8 (&f2)[4]){
        const int sA = p * 8 + wid;
        if (sA < NTILE){
            LOADFRAG(f1, sA);
            if (sA >= T1OFF) LOADFRAG(f2, sA + 61);
        }
    };

    auto DO_SLOT = [&](int s, int pc, int buf, bf16x8 (&f1)[4], bf16x8 (&f2)[4], bool pre){
        if (s >= NTILE) return;
        if (!pre){
            LOADFRAG(f1, s);
            if (s >= T1OFF) LOADFRAG(f2, s + 61);
        }
        f32x4 a1[2];
        MFMA8(f1, a1);
        if (s < T1OFF){
            const f32x4 bv = *reinterpret_cast<const f32x4*>(b3f + s * 16 + lg * 4);
            #pragma unroll
            for (int rt = 0; rt < 2; ++rt){
                f32x4 v;
                #pragma unroll
                for (int r = 0; r < 4; ++r) v[r] = fast_sigmoid(a1[rt][r] + bv[r]);
                *reinterpret_cast<f32x4*>(&lds_p[buf][rt * 16 + lm][pc]) = v;
            }
        } else {
            f32x4 a2[2];
            MFMA8(f2, a2);
            const f32x4 bv1 = *reinterpret_cast<const f32x4*>(b3f + s * 16 + lg * 4);
            const f32x4 bv2 = *reinterpret_cast<const f32x4*>(b3f + (s + 61) * 16 + lg * 4);
            const f32x4 wv  = *reinterpret_cast<const f32x4*>(pwf + (s - T1OFF) * 16 + lg * 4);
            #pragma unroll
            for (int rt = 0; rt < 2; ++rt){
                f32x4 v;
                #pragma unroll
                for (int r = 0; r < 4; ++r){
                    float u1 = fast_sigmoid(a1[rt][r] + bv1[r]);
                    float u2 = fast_sigmoid(a2[rt][r] + bv2[r]);
                    v[r] = fmaf(wv[r], u1 - u2, u2);
                }
                *reinterpret_cast<f32x4*>(&lds_p[buf][rt * 16 + lm][pc]) = v;
            }
        }
    };

    auto COMPUTE_PANEL = [&](int p, bf16x8 (&pf1)[4], bf16x8 (&pf2)[4]){
        const int buf = p & 1;
        const int sA = p * 8 + wid, sB = sA + 4;
        const int pcA = wid * 16 + lg * 4, pcB = pcA + 64;
        DO_SLOT(sA, pcA, buf, pf1, pf2, true);
        bf16x8 g1[4], g2[4];
        DO_SLOT(sB, pcB, buf, g1, g2, false);
    };

    auto DUMP = [&](int p){
        const int buf = p & 1;
        const int vb = p * 128 + l5 * 4;       // virtual col base
        int mode = 0, real = 0;
        if (vb <= 1220)                    { mode = 1; real = vb; }
        else if (vb >= 1232 && vb <= 2196) { mode = 1; real = vb - 8; }
        else if (vb == 2200)               { mode = 2; real = 2192; }
        #pragma unroll
        for (int rr = 0; rr < 4; ++rr){
            const int row = wid * 8 + rr * 2 + lh;
            f32x4 v = *reinterpret_cast<const f32x4*>(&lds_p[buf][row][l5 * 4]);
            const unsigned int off = (unsigned int)(row0 + row) * OUTW + real;
            if (mode == 1)      store16_nt(out + off, v);
            else if (mode == 2) __builtin_nontemporal_store(v[0], out + off);
        }
    };

    // ---- pipelined panel loop
    bf16x8 pf1[4], pf2[4];
    PREFETCH(0, pf1, pf2);
    COMPUTE_PANEL(0, pf1, pf2);
    for (int p = 0; p < NPANEL; ++p){
        if (p + 1 < NPANEL) PREFETCH(p + 1, pf1, pf2);   // loads issued BEFORE dump's stores
        __syncthreads();                                  // panel p ready
        DUMP(p);                                          // nt streaming stores
        if (p + 1 < NPANEL) COMPUTE_PANEL(p + 1, pf1, pf2);
    }
    #undef LOADFRAG
}

extern "C" void kernel_launch(void* const* d_in, const int* in_sizes, int n_in,
                              void* d_out, int out_size, void* d_ws, size_t ws_size,
                              hipStream_t stream)
{
    const float* x   = (const float*)d_in[0];
    const float* W1  = (const float*)d_in[1];
    const float* b1  = (const float*)d_in[2];
    const float* W2  = (const float*)d_in[3];
    const float* b2  = (const float*)d_in[4];
    const float* W3  = (const float*)d_in[5];
    const float* b3  = (const float*)d_in[6];
    const float* wgt = (const float*)d_in[7];
    const int*   i1  = (const int*)d_in[8];
    const int*   i2  = (const int*)d_in[9];
    float* out = (float*)d_out;

    unsigned char* ws = (unsigned char*)d_ws;
    unsigned short* w3f = (unsigned short*)ws;                 // 815,104 B
    float*          b3f = (float*)(ws + 815104);               // 12,736 B
    float*          pwf = (float*)(ws + 815104 + 12736);       // 3,904 B

    prep_kernel<<<NTOT, 256, 0, stream>>>(W3, b3, wgt, i1, i2, w3f, b3f, pwf);
    snn_kernel<<<NBLK, 256, 0, stream>>>(x, W1, b1, W2, b2, w3f, b3f, pwf, out);
}

// Round 11
// 210.922 us; speedup vs baseline: 1.1740x; 1.1740x over previous
//
#include <hip/hip_runtime.h>
#include <hip/hip_bf16.h>
#include <stdint.h>

#define NROWS   65536
#define RPB     32
#define TPB     1024
#define NBLK    (NROWS/RPB)       // 2048
#define H2N     100
#define KPAD    128
#define N3      1224
#define OUTW    2193
#define TAILN   969
#define T1OFF   77
#define NTILE   138               // 77 main + 61 pair logical slots
#define NTOT    199               // frag tiles in w3f
#define NPANEL  5                 // 5 panels x 32 slots (512 virtual cols each)
#define PSLOTS  32
#define PANELW  512
#define PSTR    520               // f32 row stride of LDS panel (8-bank shift/row)

typedef __attribute__((ext_vector_type(8))) short bf16x8;
typedef __attribute__((ext_vector_type(4))) float f32x4;

__device__ __forceinline__ float fast_sigmoid(float z){
    return __builtin_amdgcn_rcpf(1.0f + __expf(-z));
}
__device__ __forceinline__ unsigned short f2bf(float v){
    __hip_bfloat16 h = __float2bfloat16(v);
    return *reinterpret_cast<unsigned short*>(&h);
}

// w3f[((t*4+ks)*64+lane)*8+e] = bf16(W3[k=ks*32+(lane>>4)*8+e][srccol(t,lane&15)])
// frag tiles: 0..76 main; 77..137 gathered c1; 138..198 gathered c2.
__global__ void prep_kernel(const float* __restrict__ W3,
                            const float* __restrict__ b3,
                            const float* __restrict__ wgt,
                            const int* __restrict__ idx1,
                            const int* __restrict__ idx2,
                            unsigned short* __restrict__ w3f,
                            float* __restrict__ b3f,
                            float* __restrict__ pwf){
    const int t    = blockIdx.x;
    const int ks   = threadIdx.x >> 6;
    const int lane = threadIdx.x & 63;
    const int lm   = lane & 15, lgf = lane >> 4;

    int col = -1;
    if (t < T1OFF){
        int c = t * 16 + lm;
        if (c < N3) col = c;
    } else if (t < NTILE){
        int p = (t - T1OFF) * 16 + lm;
        if (p < TAILN){ int j = p / 17; col = idx1[j] * 17 + (p - j * 17); }
    } else {
        int p = (t - NTILE) * 16 + lm;
        if (p < TAILN){ int j = p / 17; col = idx2[j] * 17 + (p - j * 17); }
    }

    unsigned short vals[8];
    #pragma unroll
    for (int e = 0; e < 8; ++e){
        int k = ks * 32 + lgf * 8 + e;
        float v = (col >= 0 && k < H2N) ? W3[k * N3 + col] : 0.0f;
        vals[e] = f2bf(v);
    }
    *reinterpret_cast<bf16x8*>(w3f + ((size_t)(t * 4 + ks) * 64 + lane) * 8)
        = *reinterpret_cast<bf16x8*>(vals);

    if (ks == 0 && lgf == 0)
        b3f[t * 16 + lm] = (col >= 0) ? b3[col] : 0.0f;
    if (ks == 0 && lgf == 1 && t >= T1OFF && t < NTILE){
        int p = (t - T1OFF) * 16 + lm;
        pwf[(t - T1OFF) * 16 + lm] = (p < TAILN) ? wgt[p / 17] : 0.0f;
    }
}

__global__ __launch_bounds__(TPB, 4)
void snn_kernel(const float* __restrict__ x,
                const float* __restrict__ W1, const float* __restrict__ b1,
                const float* __restrict__ W2, const float* __restrict__ b2,
                const unsigned short* __restrict__ w3f,
                const float* __restrict__ b3f,
                const float* __restrict__ pwf,
                float* __restrict__ out)
{
    __shared__ __align__(16) unsigned short lds_h2[RPB][KPAD];   // 8 KB
    __shared__ float lds_h1[RPB][10];                            // 1.25 KB
    __shared__ __align__(16) float lds_p[2][RPB][PSTR];          // 130 KB (double-buffered)

    const int t    = threadIdx.x;
    const int row0 = blockIdx.x * RPB;

    // ---- layer 1
    for (int i = t; i < RPB * 10; i += TPB){
        int r = i / 10, j = i - r * 10;
        lds_h1[r][j] = fast_sigmoid(x[row0 + r] * W1[j] + b1[j]);
    }
    __syncthreads();

    // ---- layer 2 -> bf16 LDS (k 100..127 zero-padded)
    for (int i = t; i < RPB * KPAD; i += TPB){
        int r = i >> 7, c = i & 127;
        float v = 0.0f;
        if (c < H2N){
            float z = b2[c];
            #pragma unroll
            for (int j = 0; j < 10; ++j) z += lds_h1[r][j] * W2[j * H2N + c];
            v = fast_sigmoid(z);
        }
        lds_h2[r][c] = f2bf(v);
    }
    __syncthreads();

    const int lane = t & 63, wid = t >> 6;      // 16 waves
    const int lm = lane & 15, lg = lane >> 4;

    bf16x8 hfr[2][4];   // both row-tiles resident (32 VGPR)
    #pragma unroll
    for (int rt = 0; rt < 2; ++rt)
        #pragma unroll
        for (int ks = 0; ks < 4; ++ks)
            hfr[rt][ks] = *reinterpret_cast<const bf16x8*>(&lds_h2[rt * 16 + lm][ks * 32 + lg * 8]);

    #define LOADFRAG(dst, tile) do {                                              \
        const unsigned short* bp_ = w3f + ((size_t)((tile) * 4) * 64 + lane) * 8; \
        _Pragma("unroll")                                                         \
        for (int ks_ = 0; ks_ < 4; ++ks_)                                         \
            dst[ks_] = *reinterpret_cast<const bf16x8*>(bp_ + (size_t)ks_ * 512); \
    } while(0)

    auto MFMA8 = [&](bf16x8 (&cf)[4], f32x4 (&acc)[2]){
        acc[0] = f32x4{0,0,0,0}; acc[1] = f32x4{0,0,0,0};
        #pragma unroll
        for (int ks = 0; ks < 4; ++ks)
            #pragma unroll
            for (int rt = 0; rt < 2; ++rt)
                acc[rt] = __builtin_amdgcn_mfma_f32_16x16x32_bf16(cf[ks], hfr[rt][ks], acc[rt], 0, 0, 0);
    };

    // each wave owns 2 slots per panel: s = p*32 + wid*2 + {0,1}
    auto PREFETCH = [&](int p, bf16x8 (&f0)[4], bf16x8 (&f1)[4]){
        const int s0 = p * PSLOTS + wid * 2;
        if (s0 < NTILE)     LOADFRAG(f0, s0);
        if (s0 + 1 < NTILE) LOADFRAG(f1, s0 + 1);
    };

    auto DO_SLOT = [&](int s, int sl, int buf, bf16x8 (&f1)[4]){
        if (s >= NTILE) return;
        const int pc = sl * 16 + lg * 4;
        if (s < T1OFF){
            f32x4 a[2]; MFMA8(f1, a);
            const f32x4 bv = *reinterpret_cast<const f32x4*>(b3f + s * 16 + lg * 4);
            #pragma unroll
            for (int rt = 0; rt < 2; ++rt){
                f32x4 v;
                #pragma unroll
                for (int r = 0; r < 4; ++r) v[r] = fast_sigmoid(a[rt][r] + bv[r]);
                *reinterpret_cast<f32x4*>(&lds_p[buf][rt * 16 + lm][pc]) = v;
            }
        } else {
            bf16x8 f2[4];
            LOADFRAG(f2, s + 61);
            f32x4 a1[2]; MFMA8(f1, a1);
            f32x4 a2[2]; MFMA8(f2, a2);
            const f32x4 bv1 = *reinterpret_cast<const f32x4*>(b3f + s * 16 + lg * 4);
            const f32x4 bv2 = *reinterpret_cast<const f32x4*>(b3f + (s + 61) * 16 + lg * 4);
            const f32x4 wv  = *reinterpret_cast<const f32x4*>(pwf + (s - T1OFF) * 16 + lg * 4);
            #pragma unroll
            for (int rt = 0; rt < 2; ++rt){
                f32x4 v;
                #pragma unroll
                for (int r = 0; r < 4; ++r){
                    float u1 = fast_sigmoid(a1[rt][r] + bv1[r]);
                    float u2 = fast_sigmoid(a2[rt][r] + bv2[r]);
                    v[r] = fmaf(wv[r], u1 - u2, u2);
                }
                *reinterpret_cast<f32x4*>(&lds_p[buf][rt * 16 + lm][pc]) = v;
            }
        }
    };

    auto COMPUTE_PANEL = [&](int p, bf16x8 (&pf0)[4], bf16x8 (&pf1)[4]){
        const int buf = p & 1;
        const int s0 = p * PSLOTS + wid * 2;
        DO_SLOT(s0,     wid * 2,     buf, pf0);
        DO_SLOT(s0 + 1, wid * 2 + 1, buf, pf1);
    };

    // dump: wave writes rows {2*wid, 2*wid+1}, each row 2 KB contiguous,
    // dword-per-lane (conflict-free LDS, 256B-contiguous store instrs back-to-back)
    auto DUMP = [&](int p){
        const int buf = p & 1;
        #pragma unroll
        for (int rr = 0; rr < 2; ++rr){
            const int row = wid * 2 + rr;
            const unsigned int off = (unsigned int)(row0 + row) * OUTW;
            #pragma unroll
            for (int k = 0; k < 8; ++k){
                const int pc   = k * 64 + lane;
                const int vcol = p * PANELW + pc;
                const float v  = lds_p[buf][row][pc];
                if (vcol < N3)                        out[off + vcol] = v;
                else if (vcol >= 1232 && vcol <= 2200) out[off + vcol - 8] = v;
            }
        }
    };

    // ---- pipelined panel loop: loads issued before dump's stores; one barrier/panel
    bf16x8 pf0[4], pf1[4];
    PREFETCH(0, pf0, pf1);
    COMPUTE_PANEL(0, pf0, pf1);
    for (int p = 0; p < NPANEL; ++p){
        if (p + 1 < NPANEL) PREFETCH(p + 1, pf0, pf1);
        __syncthreads();                    // panel p ready; drains dump(p-1) stores
        DUMP(p);                            // fire-and-forget 2-KB row bursts
        if (p + 1 < NPANEL) COMPUTE_PANEL(p + 1, pf0, pf1);
    }
    #undef LOADFRAG
}

extern "C" void kernel_launch(void* const* d_in, const int* in_sizes, int n_in,
                              void* d_out, int out_size, void* d_ws, size_t ws_size,
                              hipStream_t stream)
{
    const float* x   = (const float*)d_in[0];
    const float* W1  = (const float*)d_in[1];
    const float* b1  = (const float*)d_in[2];
    const float* W2  = (const float*)d_in[3];
    const float* b2  = (const float*)d_in[4];
    const float* W3  = (const float*)d_in[5];
    const float* b3  = (const float*)d_in[6];
    const float* wgt = (const float*)d_in[7];
    const int*   i1  = (const int*)d_in[8];
    const int*   i2  = (const int*)d_in[9];
    float* out = (float*)d_out;

    unsigned char* ws = (unsigned char*)d_ws;
    unsigned short* w3f = (unsigned short*)ws;                 // 815,104 B
    float*          b3f = (float*)(ws + 815104);               // 12,736 B
    float*          pwf = (float*)(ws + 815104 + 12736);       // 3,904 B

    prep_kernel<<<NTOT, 256, 0, stream>>>(W3, b3, wgt, i1, i2, w3f, b3f, pwf);
    snn_kernel<<<NBLK, TPB, 0, stream>>>(x, W1, b1, W2, b2, w3f, b3f, pwf, out);
}